// Round 9
// baseline (2843.618 us; speedup 1.0000x reference)
//
#include <hip/hip_runtime.h>
#include <stdint.h>

// Problem constants
#define VOCAB 50000
#define EMBD  128
#define HID   256
#define G4    1024   // 4*HID
#define BATCH 256
#define TSEQ  512
#define OUTD  64

typedef __attribute__((ext_vector_type(4))) float f32x4;
typedef __attribute__((ext_vector_type(8))) short short8;
typedef __attribute__((ext_vector_type(4))) unsigned short ushort4_t;

__device__ inline unsigned short f2bf(float f) {
  unsigned u = __float_as_uint(f);
  u += 0x7fffu + ((u >> 16) & 1u);     // round-nearest-even
  return (unsigned short)(u >> 16);
}
__device__ inline float bf2f(unsigned short u) {
  return __uint_as_float(((unsigned)u) << 16);
}
__device__ inline short8 pack2(f32x4 a, f32x4 b) {
  short8 r;
  r[0] = (short)f2bf(a[0]); r[1] = (short)f2bf(a[1]);
  r[2] = (short)f2bf(a[2]); r[3] = (short)f2bf(a[3]);
  r[4] = (short)f2bf(b[0]); r[5] = (short)f2bf(b[1]);
  r[6] = (short)f2bf(b[2]); r[7] = (short)f2bf(b[3]);
  return r;
}
__device__ inline float sigmoid_(float x) {
  return __builtin_amdgcn_rcpf(1.0f + __expf(-x));
}
__device__ inline float tanh_(float x) {
  float e = __expf(2.0f * x);
  return (e - 1.0f) * __builtin_amdgcn_rcpf(e + 1.0f);
}

// Wave-uniform LDS spin (volatile -> ds_read each poll; s_sleep backoff).
// Trailing clobber stops the compiler hoisting dependent ds_reads above it.
__device__ inline void spin_ge(const volatile int* f, int target) {
  if (*f < target) {
    do { __builtin_amdgcn_s_sleep(1); } while (*f < target);
  }
  asm volatile("" ::: "memory");
}

// Wx layout: Wx[v][u*4 + nt], u = h-unit 0..255, nt in {i,f,g,o}; oj = nt*256+u.

// ---------------------------------------------------------------------------
// K1: Wx[v][u*4+nt] = bf16( b_ih[oj] + b_hh[oj] + emb[v] . W_ih[oj] )
// ---------------------------------------------------------------------------
__global__ __launch_bounds__(256) void wx_k1(
    const float* __restrict__ emb, const float* __restrict__ Wih,
    const float* __restrict__ bih, const float* __restrict__ bhh,
    unsigned short* __restrict__ Wx) {
  const int vb = blockIdx.x * 16;
  const int w1 = threadIdx.x >> 6, lane = threadIdx.x & 63;
  const int quad = lane >> 4, n = lane & 15;
  const int combo = blockIdx.y * 4 + w1;        // 0..15 -> units combo*16..+15

  float bias[4];
  short8 bfr[4][4];
#pragma unroll
  for (int nt = 0; nt < 4; ++nt) {
    const int oj = nt * 256 + combo * 16 + n;
    bias[nt] = bih[oj] + bhh[oj];
#pragma unroll
    for (int kc = 0; kc < 4; ++kc) {
      const f32x4* wp = (const f32x4*)(Wih + (size_t)oj * EMBD + kc * 32 + quad * 8);
      bfr[nt][kc] = pack2(wp[0], wp[1]);
    }
  }
  short8 af[4];
#pragma unroll
  for (int kc = 0; kc < 4; ++kc) {
    const f32x4* ep = (const f32x4*)(emb + (size_t)(vb + n) * EMBD + kc * 32 + quad * 8);
    af[kc] = pack2(ep[0], ep[1]);
  }
  f32x4 acc[4];
#pragma unroll
  for (int nt = 0; nt < 4; ++nt) acc[nt] = (f32x4){0.f, 0.f, 0.f, 0.f};
#pragma unroll
  for (int kc = 0; kc < 4; ++kc)
#pragma unroll
    for (int nt = 0; nt < 4; ++nt)
      acc[nt] = __builtin_amdgcn_mfma_f32_16x16x32_bf16(af[kc], bfr[nt][kc], acc[nt], 0, 0, 0);
#pragma unroll
  for (int rr = 0; rr < 4; ++rr) {
    ushort4_t o;
#pragma unroll
    for (int nt = 0; nt < 4; ++nt) o[nt] = f2bf(acc[nt][rr] + bias[nt]);
    *(ushort4_t*)&Wx[(size_t)(vb + quad * 4 + rr) * G4 + (combo * 16 + n) * 4] = o;
  }
}

// ---------------------------------------------------------------------------
// K2: self-contained LSTM recurrence, BARRIER-FREE K-loop.
// 16 WGs x 512 threads; WG = 16 batch rows, all 256 h-units.
// Wave w is the SOLE producer of h-chunk w (units w*32..+31) and chunk kc is
// consumed only by K-chunk kc's A-read -> per-chunk ready flags replace the
// per-step __syncthreads (which lockstepped the 2 waves/SIMD so they stalled
// at the same points; R6-R8 plateau ~9K cyc/step vs ~3.1K pipe floor).
//   - h ring depth 3 (slot = t%3), wf[slot][chunk] = ready stamp (t+1 set by
//     producer after lgkm-drained writes; reader spins wf >= t).
//   - rc[slot] monotone reader counters: wave bumps rc[p] after its last
//     A-read of h(t); producer of h(t+1) spins rc[slot(t+1)] >= 8*c(t)
//     (uses of that slot so far) before overwriting h(t-2). 2-step skew
//     tolerance; most-behind wave never blocks -> deadlock-free.
// W_hh: K-chunks 0..5 in VGPRs/AGPRs (192/lane), 6..7 in LDS (128 KB).
// Register arrays constant-indexed only (R1); global loads consumed only
// cross-step (R7); no s_barrier in loop -> no vmcnt/lgkm drain at all.
// ---------------------------------------------------------------------------
__global__ __launch_bounds__(512, 2) void lstm_k2(
    const int* __restrict__ x, const float* __restrict__ Whh,
    const unsigned short* __restrict__ Wx,
    float* __restrict__ lastH) {               // [256][256]
  const int group = blockIdx.x;                // 16 groups of 16 batch rows
  const int rowbase = group * 16;
  const int tid = threadIdx.x;
  const int w = tid >> 6, lane = tid & 63;
  const int quad = lane >> 4, n = lane & 15;

  __shared__ __attribute__((aligned(16))) unsigned short h_lds[3][16][264];   // 25.3 KB
  __shared__ __attribute__((aligned(16))) unsigned short wlds[8][2][4][2][64][8]; // 128 KB
  __shared__ int zpos[16];
  __shared__ int wf[3][8];   // h-chunk ready stamps per slot
  __shared__ int rc[3];      // readers-done monotone counters per slot

  if (tid < 16) zpos[tid] = 1 << 30;
  if (tid < 8) { wf[0][tid] = 0; wf[1][tid] = -1; wf[2][tid] = -1; }
  if (tid < 3) rc[tid] = 0;
  __syncthreads();
  // scan tokens for the pad position (first zero)
  for (int i = tid; i < 16 * TSEQ; i += 512) {
    const int row = i >> 9, tc = i & 511;
    if (x[(size_t)(rowbase + row) * TSEQ + tc] == 0) atomicMin(&zpos[row], tc);
  }
  // zero h(0) (slot 0 = first 16*264 entries)
  for (int i = tid; i < 16 * 264; i += 512) ((unsigned short*)h_lds)[i] = 0;

  // LDS weights: K-chunks 6,7 (B-frag layout)
#pragma unroll
  for (int gl = 0; gl < 2; ++gl)
#pragma unroll
    for (int nt = 0; nt < 4; ++nt)
#pragma unroll
      for (int kcl = 0; kcl < 2; ++kcl) {
        const int oj = nt * 256 + (2 * w + gl) * 16 + n;
        const f32x4* wp = (const f32x4*)(Whh + (size_t)oj * HID + (6 + kcl) * 32 + quad * 8);
        *(short8*)&wlds[w][gl][nt][kcl][lane][0] = pack2(wp[0], wp[1]);
      }

  // register weights: K-chunks 0..5.  B[k][col=n] = Whh[oj(n)][k].
  short8 bfr[2][4][6];
#pragma unroll
  for (int gl = 0; gl < 2; ++gl)
#pragma unroll
    for (int nt = 0; nt < 4; ++nt) {
      const int oj = nt * 256 + (2 * w + gl) * 16 + n;
      const float* wrow = Whh + (size_t)oj * HID;
#pragma unroll
      for (int kc = 0; kc < 6; ++kc) {
        const f32x4* wp = (const f32x4*)(wrow + kc * 32 + quad * 8);
        bfr[gl][nt][kc] = pack2(wp[0], wp[1]);
      }
    }

  float cst[2][4];
  float lastreg[2][4];
#pragma unroll
  for (int gl = 0; gl < 2; ++gl)
#pragma unroll
    for (int rr = 0; rr < 4; ++rr) { cst[gl][rr] = 0.f; lastreg[gl][rr] = 0.f; }

  __syncthreads();   // zpos, h(0), wlds, flags ready
  int idx4[4];
#pragma unroll
  for (int rr = 0; rr < 4; ++rr) idx4[rr] = zpos[quad * 4 + rr] - 1;

  // initial Wx load (t=0) + token prefetch for t=1
  ushort4_t wxbuf[2][4];
  int tokc[4];
#pragma unroll
  for (int rr = 0; rr < 4; ++rr) {
    const int t0 = x[(size_t)(rowbase + quad * 4 + rr) * TSEQ + 0];
#pragma unroll
    for (int gl = 0; gl < 2; ++gl)
      wxbuf[gl][rr] = *(const ushort4_t*)(Wx + (size_t)t0 * G4 + ((2 * w + gl) * 16 + n) * 4);
    tokc[rr] = x[(size_t)(rowbase + quad * 4 + rr) * TSEQ + 1];
  }

  int p = 0, pn = 1;
  for (int t = 0; t < TSEQ; ++t) {
    const int tnn = (t + 2 < TSEQ) ? (t + 2) : (TSEQ - 1);

    // ---- gl = 0 : spin-gated A-reads (first touch of each chunk) ----
    {
      f32x4 acc[4];
#pragma unroll
      for (int rr = 0; rr < 4; ++rr) {
        const ushort4_t g4 = wxbuf[0][rr];
#pragma unroll
        for (int nt = 0; nt < 4; ++nt) acc[nt][rr] = bf2f(g4[nt]);
      }
#pragma unroll
      for (int rr = 0; rr < 4; ++rr)
        wxbuf[0][rr] = *(const ushort4_t*)(Wx + (size_t)tokc[rr] * G4 + ((2 * w + 0) * 16 + n) * 4);

#pragma unroll
      for (int kc = 0; kc < 6; ++kc) {
        spin_ge(&wf[p][kc], t);
        const short8 a = *(const short8*)&h_lds[p][n][kc * 32 + quad * 8];
#pragma unroll
        for (int nt = 0; nt < 4; ++nt)
          acc[nt] = __builtin_amdgcn_mfma_f32_16x16x32_bf16(a, bfr[0][nt][kc], acc[nt], 0, 0, 0);
      }
#pragma unroll
      for (int kcl = 0; kcl < 2; ++kcl) {
        spin_ge(&wf[p][6 + kcl], t);
        const short8 a = *(const short8*)&h_lds[p][n][(6 + kcl) * 32 + quad * 8];
#pragma unroll
        for (int nt = 0; nt < 4; ++nt) {
          const short8 b = *(const short8*)&wlds[w][0][nt][kcl][lane][0];
          acc[nt] = __builtin_amdgcn_mfma_f32_16x16x32_bf16(a, b, acc[nt], 0, 0, 0);
        }
      }

      // gate slot pn reuse: all 8 waves must be done reading h(t-2)
      {
        const int c = (t >= 2) ? ((t - 2) / 3 + 1) : 0;
        spin_ge(&rc[pn], 8 * c);
      }

      const int u = (2 * w + 0) * 16 + n;
#pragma unroll
      for (int rr = 0; rr < 4; ++rr) {
        const float gi = acc[0][rr], gf = acc[1][rr], gg = acc[2][rr], go = acc[3][rr];
        const float ci = sigmoid_(gf) * cst[0][rr] + sigmoid_(gi) * tanh_(gg);
        cst[0][rr] = ci;
        const float hv = sigmoid_(go) * tanh_(ci);
        h_lds[pn][quad * 4 + rr][u] = f2bf(hv);
        lastreg[0][rr] = (t == idx4[rr]) ? hv : lastreg[0][rr];
      }
    }

    // ---- gl = 1 : chunks already flag-checked this step ----
    {
      f32x4 acc[4];
#pragma unroll
      for (int rr = 0; rr < 4; ++rr) {
        const ushort4_t g4 = wxbuf[1][rr];
#pragma unroll
        for (int nt = 0; nt < 4; ++nt) acc[nt][rr] = bf2f(g4[nt]);
      }
#pragma unroll
      for (int rr = 0; rr < 4; ++rr)
        wxbuf[1][rr] = *(const ushort4_t*)(Wx + (size_t)tokc[rr] * G4 + ((2 * w + 1) * 16 + n) * 4);

#pragma unroll
      for (int kc = 0; kc < 6; ++kc) {
        const short8 a = *(const short8*)&h_lds[p][n][kc * 32 + quad * 8];
#pragma unroll
        for (int nt = 0; nt < 4; ++nt)
          acc[nt] = __builtin_amdgcn_mfma_f32_16x16x32_bf16(a, bfr[1][nt][kc], acc[nt], 0, 0, 0);
      }
#pragma unroll
      for (int kcl = 0; kcl < 2; ++kcl) {
        const short8 a = *(const short8*)&h_lds[p][n][(6 + kcl) * 32 + quad * 8];
#pragma unroll
        for (int nt = 0; nt < 4; ++nt) {
          const short8 b = *(const short8*)&wlds[w][1][nt][kcl][lane][0];
          acc[nt] = __builtin_amdgcn_mfma_f32_16x16x32_bf16(a, b, acc[nt], 0, 0, 0);
        }
      }

      // this wave is done reading h(t): bump the reader counter for slot p
      asm volatile("" ::: "memory");
      if (lane == 0)
        __hip_atomic_fetch_add(&rc[p], 1, __ATOMIC_RELAXED, __HIP_MEMORY_SCOPE_WORKGROUP);

      const int u = (2 * w + 1) * 16 + n;
#pragma unroll
      for (int rr = 0; rr < 4; ++rr) {
        const float gi = acc[0][rr], gf = acc[1][rr], gg = acc[2][rr], go = acc[3][rr];
        const float ci = sigmoid_(gf) * cst[1][rr] + sigmoid_(gi) * tanh_(gg);
        cst[1][rr] = ci;
        const float hv = sigmoid_(go) * tanh_(ci);
        h_lds[pn][quad * 4 + rr][u] = f2bf(hv);
        lastreg[1][rr] = (t == idx4[rr]) ? hv : lastreg[1][rr];
      }
    }

    // token prefetch for t+2
#pragma unroll
    for (int rr = 0; rr < 4; ++rr)
      tokc[rr] = x[(size_t)(rowbase + quad * 4 + rr) * TSEQ + tnn];

    // publish chunk w of h(t+1): drain own LDS writes, then stamp the flag
    asm volatile("s_waitcnt lgkmcnt(0)" ::: "memory");
    if (lane == 0) *(volatile int*)&wf[pn][w] = t + 1;

    p = pn;
    pn = pn + 1; if (pn == 3) pn = 0;
  }

  // final: write gathered last-valid h (f32, pre-bf16-rounding)
#pragma unroll
  for (int gl = 0; gl < 2; ++gl) {
    const int u = (2 * w + gl) * 16 + n;
#pragma unroll
    for (int rr = 0; rr < 4; ++rr)
      lastH[(size_t)(rowbase + quad * 4 + rr) * HID + u] = lastreg[gl][rr];
  }
}

// ---------------------------------------------------------------------------
// K3: logits + softmax. One wave per batch row; lane j = output j.
// ---------------------------------------------------------------------------
__global__ __launch_bounds__(64) void head_k3(
    const float* __restrict__ lastH, const float* __restrict__ Wout,
    const float* __restrict__ bout, float* __restrict__ out) {
  const int b = blockIdx.x, j = threadIdx.x;
  const f32x4* hv = (const f32x4*)(lastH + (size_t)b * HID);
  const f32x4* wv = (const f32x4*)(Wout + (size_t)j * HID);
  float acc = bout[j];
#pragma unroll 8
  for (int k = 0; k < HID / 4; ++k) {
    const f32x4 a = hv[k], ww = wv[k];
    acc += a[0] * ww[0] + a[1] * ww[1] + a[2] * ww[2] + a[3] * ww[3];
  }
  float m = acc;
  for (int s = 32; s > 0; s >>= 1) m = fmaxf(m, __shfl_xor(m, s, 64));
  const float e = __expf(acc - m);
  float ssum = e;
  for (int s = 32; s > 0; s >>= 1) ssum += __shfl_xor(ssum, s, 64);
  out[(size_t)b * OUTD + j] = e / ssum;
}

// ---------------------------------------------------------------------------
extern "C" void kernel_launch(void* const* d_in, const int* in_sizes, int n_in,
                              void* d_out, int out_size, void* d_ws, size_t ws_size,
                              hipStream_t stream) {
  const int*   x    = (const int*)d_in[0];
  const float* emb  = (const float*)d_in[1];
  const float* Wih  = (const float*)d_in[2];
  const float* Whh  = (const float*)d_in[3];
  const float* bih  = (const float*)d_in[4];
  const float* bhh  = (const float*)d_in[5];
  const float* Wout = (const float*)d_in[6];
  const float* bout = (const float*)d_in[7];
  float* out = (float*)d_out;

  // workspace carve (~97.9 MiB)
  char* ws = (char*)d_ws;
  unsigned short* Wx = (unsigned short*)ws;                 // 102,400,000 B
  float* lastH = (float*)(ws + 102400000);                  // 262,144 B

  hipLaunchKernelGGL(wx_k1, dim3(3125, 4), dim3(256), 0, stream,
                     emb, Wih, bih, bhh, Wx);
  hipLaunchKernelGGL(lstm_k2, dim3(16), dim3(512), 0, stream,
                     x, Whh, Wx, lastH);
  hipLaunchKernelGGL(head_k3, dim3(BATCH), dim3(OUTD), 0, stream,
                     lastH, Wout, bout, out);
}

// Round 10
// 1968.366 us; speedup vs baseline: 1.4447x; 1.4447x over previous
//
#include <hip/hip_runtime.h>
#include <stdint.h>

// Problem constants
#define VOCAB 50000
#define EMBD  128
#define HID   256
#define G4    1024   // 4*HID
#define BATCH 256
#define TSEQ  512
#define OUTD  64

typedef __attribute__((ext_vector_type(4))) float f32x4;
typedef __attribute__((ext_vector_type(8))) short short8;
typedef __attribute__((ext_vector_type(4))) unsigned short ushort4_t;

__device__ inline unsigned short f2bf(float f) {
  unsigned u = __float_as_uint(f);
  u += 0x7fffu + ((u >> 16) & 1u);     // round-nearest-even
  return (unsigned short)(u >> 16);
}
__device__ inline float bf2f(unsigned short u) {
  return __uint_as_float(((unsigned)u) << 16);
}
__device__ inline short8 pack2(f32x4 a, f32x4 b) {
  short8 r;
  r[0] = (short)f2bf(a[0]); r[1] = (short)f2bf(a[1]);
  r[2] = (short)f2bf(a[2]); r[3] = (short)f2bf(a[3]);
  r[4] = (short)f2bf(b[0]); r[5] = (short)f2bf(b[1]);
  r[6] = (short)f2bf(b[2]); r[7] = (short)f2bf(b[3]);
  return r;
}

// LDS-only barrier (R6 win): h double-buffer needs only LDS ordering; global
// prefetch loads stay in flight across it. R7 lesson: global loads must be
// consumed only in a LATER step. R9 lesson: flag/spin pipelines lose to this.
__device__ inline void barrier_lds_only() {
  asm volatile("s_waitcnt lgkmcnt(0)\n\ts_barrier" ::: "memory");
}

// Wx layout: Wx[v][u*4 + nt], u = h-unit 0..255, nt in {i,f,g,o}; oj = nt*256+u.

// ---------------------------------------------------------------------------
// K1: Wx[v][u*4+nt] = bf16( b_ih[oj] + b_hh[oj] + emb[v] . W_ih[oj] )
// grid (782, 4): each block packs its W_ih fragments ONCE and loops 4 vocab
// tiles (4x less redundant weight fetch + bf16 pack than 3125x4).
// 781*4+1 tiles = 3125 tiles = 50,000 rows exactly; loop breaks at vb>=VOCAB.
// ---------------------------------------------------------------------------
__global__ __launch_bounds__(256) void wx_k1(
    const float* __restrict__ emb, const float* __restrict__ Wih,
    const float* __restrict__ bih, const float* __restrict__ bhh,
    unsigned short* __restrict__ Wx) {
  const int w1 = threadIdx.x >> 6, lane = threadIdx.x & 63;
  const int quad = lane >> 4, n = lane & 15;
  const int combo = blockIdx.y * 4 + w1;        // 0..15 -> units combo*16..+15

  float bias[4];
  short8 bfr[4][4];
#pragma unroll
  for (int nt = 0; nt < 4; ++nt) {
    const int oj = nt * 256 + combo * 16 + n;
    bias[nt] = bih[oj] + bhh[oj];
#pragma unroll
    for (int kc = 0; kc < 4; ++kc) {
      const f32x4* wp = (const f32x4*)(Wih + (size_t)oj * EMBD + kc * 32 + quad * 8);
      bfr[nt][kc] = pack2(wp[0], wp[1]);
    }
  }

  for (int vt = 0; vt < 4; ++vt) {
    const int vb = blockIdx.x * 64 + vt * 16;
    if (vb >= VOCAB) break;                     // tiles align: 49,984+16 = 50,000
    short8 af[4];
#pragma unroll
    for (int kc = 0; kc < 4; ++kc) {
      const f32x4* ep = (const f32x4*)(emb + (size_t)(vb + n) * EMBD + kc * 32 + quad * 8);
      af[kc] = pack2(ep[0], ep[1]);
    }
    f32x4 acc[4];
#pragma unroll
    for (int nt = 0; nt < 4; ++nt) acc[nt] = (f32x4){0.f, 0.f, 0.f, 0.f};
#pragma unroll
    for (int kc = 0; kc < 4; ++kc)
#pragma unroll
      for (int nt = 0; nt < 4; ++nt)
        acc[nt] = __builtin_amdgcn_mfma_f32_16x16x32_bf16(af[kc], bfr[nt][kc], acc[nt], 0, 0, 0);
#pragma unroll
    for (int rr = 0; rr < 4; ++rr) {
      ushort4_t o;
#pragma unroll
      for (int nt = 0; nt < 4; ++nt) o[nt] = f2bf(acc[nt][rr] + bias[nt]);
      *(ushort4_t*)&Wx[(size_t)(vb + quad * 4 + rr) * G4 + (combo * 16 + n) * 4] = o;
    }
  }
}

// ---------------------------------------------------------------------------
// K2: self-contained LSTM recurrence (R6 structure, best known: 8.98K cyc/step).
// 16 WGs x 512 threads; WG = 16 batch rows, ALL 256 h-units, one lgkm-only
// barrier/step. W_hh: K-chunks 0..5 in VGPRs/AGPRs (192/lane), 6..7 in LDS.
// Wave w owns units [w*32,(w+1)*32) as two half-passes gl=0,1.
// R10 deltas vs R6: fused pointwise (5 exp + 3 rcp, validated in R8),
// token offsets prescaled. Everything else byte-identical to R6.
// ---------------------------------------------------------------------------
__global__ __launch_bounds__(512, 2) void lstm_k2(
    const int* __restrict__ x, const float* __restrict__ Whh,
    const unsigned short* __restrict__ Wx,
    float* __restrict__ lastH) {               // [256][256]
  const int group = blockIdx.x;                // 16 groups of 16 batch rows
  const int rowbase = group * 16;
  const int tid = threadIdx.x;
  const int w = tid >> 6, lane = tid & 63;
  const int quad = lane >> 4, n = lane & 15;

  __shared__ __attribute__((aligned(16))) unsigned short h_lds[2][16][264];   // 16.5 KB
  __shared__ __attribute__((aligned(16))) unsigned short wlds[8][2][4][2][64][8]; // 128 KB
  __shared__ int zpos[16];

  if (tid < 16) zpos[tid] = 1 << 30;
  __syncthreads();
  // scan tokens for the pad position (first zero)
  for (int i = tid; i < 16 * TSEQ; i += 512) {
    const int row = i >> 9, tc = i & 511;
    if (x[(size_t)(rowbase + row) * TSEQ + tc] == 0) atomicMin(&zpos[row], tc);
  }
  // zero h(0) (buffer 0)
  for (int i = tid; i < 16 * 264; i += 512) ((unsigned short*)h_lds)[i] = 0;

  // LDS weights: K-chunks 6,7 (B-frag layout)
#pragma unroll
  for (int gl = 0; gl < 2; ++gl)
#pragma unroll
    for (int nt = 0; nt < 4; ++nt)
#pragma unroll
      for (int kcl = 0; kcl < 2; ++kcl) {
        const int oj = nt * 256 + (2 * w + gl) * 16 + n;
        const f32x4* wp = (const f32x4*)(Whh + (size_t)oj * HID + (6 + kcl) * 32 + quad * 8);
        *(short8*)&wlds[w][gl][nt][kcl][lane][0] = pack2(wp[0], wp[1]);
      }

  // register weights: K-chunks 0..5.  B[k][col=n] = Whh[oj(n)][k].
  short8 bfr[2][4][6];
#pragma unroll
  for (int gl = 0; gl < 2; ++gl)
#pragma unroll
    for (int nt = 0; nt < 4; ++nt) {
      const int oj = nt * 256 + (2 * w + gl) * 16 + n;
      const float* wrow = Whh + (size_t)oj * HID;
#pragma unroll
      for (int kc = 0; kc < 6; ++kc) {
        const f32x4* wp = (const f32x4*)(wrow + kc * 32 + quad * 8);
        bfr[gl][nt][kc] = pack2(wp[0], wp[1]);
      }
    }

  float cst[2][4];
  float lastreg[2][4];
#pragma unroll
  for (int gl = 0; gl < 2; ++gl)
#pragma unroll
    for (int rr = 0; rr < 4; ++rr) { cst[gl][rr] = 0.f; lastreg[gl][rr] = 0.f; }

  __syncthreads();   // zpos, h(0), wlds ready
  int idx4[4];
#pragma unroll
  for (int rr = 0; rr < 4; ++rr) idx4[rr] = zpos[quad * 4 + rr] - 1;

  // initial Wx load (t=0) + token-offset prefetch for t=1 (prescaled to elems)
  ushort4_t wxbuf[2][4];
  int toko[4];
#pragma unroll
  for (int rr = 0; rr < 4; ++rr) {
    const int t0 = x[(size_t)(rowbase + quad * 4 + rr) * TSEQ + 0];
#pragma unroll
    for (int gl = 0; gl < 2; ++gl)
      wxbuf[gl][rr] = *(const ushort4_t*)(Wx + (size_t)t0 * G4 + ((2 * w + gl) * 16 + n) * 4);
    toko[rr] = x[(size_t)(rowbase + quad * 4 + rr) * TSEQ + 1] * G4;
  }

  // fused LSTM pointwise: 5 exp + 3 rcp (vs naive 5+5), validated in R8:
  //   c' = c*rcp(1+e^-f) + (e^{2g}-1)*rcp((1+e^-i)(e^{2g}+1))
  //   h  = (e^{2c'}-1)*rcp((1+e^-o)(e^{2c'}+1))
  for (int t = 0; t < TSEQ; ++t) {
    const int p = t & 1, pn = p ^ 1;
    const int tnn = (t + 2 < TSEQ) ? (t + 2) : (TSEQ - 1);

#pragma unroll
    for (int gl = 0; gl < 2; ++gl) {
      // acc init from prefetched Wx (has both biases)
      f32x4 acc[4];
#pragma unroll
      for (int rr = 0; rr < 4; ++rr) {
        const ushort4_t g4 = wxbuf[gl][rr];
#pragma unroll
        for (int nt = 0; nt < 4; ++nt) acc[nt][rr] = bf2f(g4[nt]);
      }
      // re-issue prefetch for t+1 (offset ready since last step; consumed
      // only next step -> full-step latency overlap, nothing drains it)
#pragma unroll
      for (int rr = 0; rr < 4; ++rr)
        wxbuf[gl][rr] = *(const ushort4_t*)(Wx + (size_t)(unsigned)toko[rr] + ((2 * w + gl) * 16 + n) * 4);

      // GEMM: K-chunks 0..5 from register B-frags
#pragma unroll
      for (int kc = 0; kc < 6; ++kc) {
        const short8 a = *(const short8*)&h_lds[p][n][kc * 32 + quad * 8];
#pragma unroll
        for (int nt = 0; nt < 4; ++nt)
          acc[nt] = __builtin_amdgcn_mfma_f32_16x16x32_bf16(a, bfr[gl][nt][kc], acc[nt], 0, 0, 0);
      }
      // K-chunks 6..7 from LDS B-frags
#pragma unroll
      for (int kcl = 0; kcl < 2; ++kcl) {
        const short8 a = *(const short8*)&h_lds[p][n][(6 + kcl) * 32 + quad * 8];
#pragma unroll
        for (int nt = 0; nt < 4; ++nt) {
          const short8 b = *(const short8*)&wlds[w][gl][nt][kcl][lane][0];
          acc[nt] = __builtin_amdgcn_mfma_f32_16x16x32_bf16(a, b, acc[nt], 0, 0, 0);
        }
      }
      // fused pointwise: lane owns unit u=(2w+gl)*16+n for rows quad*4+rr
      const int u = (2 * w + gl) * 16 + n;
#pragma unroll
      for (int rr = 0; rr < 4; ++rr) {
        const float ei = __expf(-acc[0][rr]), ef = __expf(-acc[1][rr]);
        const float eg2 = __expf(2.0f * acc[2][rr]), eo = __expf(-acc[3][rr]);
        const float r1 = __builtin_amdgcn_rcpf(1.0f + ef);
        const float r2 = __builtin_amdgcn_rcpf((1.0f + ei) * (eg2 + 1.0f));
        const float ci = cst[gl][rr] * r1 + (eg2 - 1.0f) * r2;
        cst[gl][rr] = ci;
        const float ec2 = __expf(2.0f * ci);
        const float r3 = __builtin_amdgcn_rcpf((1.0f + eo) * (ec2 + 1.0f));
        const float hv = (ec2 - 1.0f) * r3;
        h_lds[pn][quad * 4 + rr][u] = f2bf(hv);
        lastreg[gl][rr] = (t == idx4[rr]) ? hv : lastreg[gl][rr];
      }
    }
    // token-offset prefetch for t+2
#pragma unroll
    for (int rr = 0; rr < 4; ++rr)
      toko[rr] = x[(size_t)(rowbase + quad * 4 + rr) * TSEQ + tnn] * G4;

    barrier_lds_only();  // h(t+1) complete; global prefetches stay in flight
  }

  // final: write gathered last-valid h (f32, pre-bf16-rounding)
#pragma unroll
  for (int gl = 0; gl < 2; ++gl) {
    const int u = (2 * w + gl) * 16 + n;
#pragma unroll
    for (int rr = 0; rr < 4; ++rr)
      lastH[(size_t)(rowbase + quad * 4 + rr) * HID + u] = lastreg[gl][rr];
  }
}

// ---------------------------------------------------------------------------
// K3: logits + softmax. One wave per batch row; lane j = output j.
// ---------------------------------------------------------------------------
__global__ __launch_bounds__(64) void head_k3(
    const float* __restrict__ lastH, const float* __restrict__ Wout,
    const float* __restrict__ bout, float* __restrict__ out) {
  const int b = blockIdx.x, j = threadIdx.x;
  const f32x4* hv = (const f32x4*)(lastH + (size_t)b * HID);
  const f32x4* wv = (const f32x4*)(Wout + (size_t)j * HID);
  float acc = bout[j];
#pragma unroll 8
  for (int k = 0; k < HID / 4; ++k) {
    const f32x4 a = hv[k], ww = wv[k];
    acc += a[0] * ww[0] + a[1] * ww[1] + a[2] * ww[2] + a[3] * ww[3];
  }
  float m = acc;
  for (int s = 32; s > 0; s >>= 1) m = fmaxf(m, __shfl_xor(m, s, 64));
  const float e = __expf(acc - m);
  float ssum = e;
  for (int s = 32; s > 0; s >>= 1) ssum += __shfl_xor(ssum, s, 64);
  out[(size_t)b * OUTD + j] = e / ssum;
}

// ---------------------------------------------------------------------------
extern "C" void kernel_launch(void* const* d_in, const int* in_sizes, int n_in,
                              void* d_out, int out_size, void* d_ws, size_t ws_size,
                              hipStream_t stream) {
  const int*   x    = (const int*)d_in[0];
  const float* emb  = (const float*)d_in[1];
  const float* Wih  = (const float*)d_in[2];
  const float* Whh  = (const float*)d_in[3];
  const float* bih  = (const float*)d_in[4];
  const float* bhh  = (const float*)d_in[5];
  const float* Wout = (const float*)d_in[6];
  const float* bout = (const float*)d_in[7];
  float* out = (float*)d_out;

  // workspace carve (~97.9 MiB)
  char* ws = (char*)d_ws;
  unsigned short* Wx = (unsigned short*)ws;                 // 102,400,000 B
  float* lastH = (float*)(ws + 102400000);                  // 262,144 B

  hipLaunchKernelGGL(wx_k1, dim3(782, 4), dim3(256), 0, stream,
                     emb, Wih, bih, bhh, Wx);
  hipLaunchKernelGGL(lstm_k2, dim3(16), dim3(512), 0, stream,
                     x, Whh, Wx, lastH);
  hipLaunchKernelGGL(head_k3, dim3(BATCH), dim3(OUTD), 0, stream,
                     lastH, Wout, bout, out);
}